// Round 9
// baseline (3885.834 us; speedup 1.0000x reference)
//
#include <hip/hip_runtime.h>
#include <hip/hip_bf16.h>
#include <hip/hip_fp8.h>
#include <hip/hip_cooperative_groups.h>
#include <cstdint>

namespace cg = cooperative_groups;

#define B_   128
#define T_   80
#define E_   100
#define U_   2048
#define G4_  8192

// scales: A-side (x,h) x16, B-side (weights) x32; acc * 1/512 restores z
#define SA_   16.0f
#define SB_   32.0f
#define INV_SASB_ (1.0f / 512.0f)

typedef __attribute__((ext_vector_type(4))) float f32x4;

__device__ __forceinline__ unsigned char f2fp8(float x) {
    __hip_fp8_e4m3 q(x);
    return q.__x;
}

// ---------------- embedding -> A-fragment-packed fp8 X (kb0 = 8 frags) -----
__global__ __launch_bounds__(256)
void embed_pack(const int* __restrict__ tokens, const float* __restrict__ emb,
                unsigned char* __restrict__ Xp) {
    int gtid = blockIdx.x * 256 + threadIdx.x;   // one 8-byte chunk each
    if (gtid >= T_ * 8 * 8 * 64) return;
    int lane = gtid & 63;
    int rest = gtid >> 6;
    int i    = rest & 7;  rest >>= 3;
    int mtg  = rest & 7;
    int t    = rest >> 3;
    int row  = (mtg >> 2) * 64 + (mtg & 3) * 16 + (lane & 15);
    int k0   = i * 32 + (lane >> 4) * 8;
    const float* erow = emb + (size_t)tokens[row * T_ + t] * E_;
    unsigned char v[8];
#pragma unroll
    for (int j = 0; j < 8; ++j) {
        int e = k0 + j;
        v[j] = f2fp8(e < E_ ? SA_ * erow[e] : 0.f);
    }
    *reinterpret_cast<uint2*>(Xp + (size_t)gtid * 8) = *reinterpret_cast<const uint2*>(v);
}

// ---------------- weight pack: fp32 [K][Ncols] -> fp8 MFMA B-frag layout ----
__global__ __launch_bounds__(256)
void pack_w(const float* __restrict__ W, int K, int Ncols, int NG, int KB,
            unsigned char* __restrict__ out) {
    int gtid = blockIdx.x * 256 + threadIdx.x;
    int lane = gtid & 63;
    int rest = gtid >> 6;
    int g = rest % NG; rest /= NG;
    int i = rest % KB;
    int ut = rest / KB;
    if (ut >= U_ / 16) return;
    int col = g * U_ + ut * 16 + (lane & 15);
    int k0 = i * 32 + (lane >> 4) * 8;
    unsigned char v[8];
#pragma unroll
    for (int j = 0; j < 8; ++j) {
        int k = k0 + j;
        v[j] = f2fp8(k < K ? SB_ * W[(size_t)k * Ncols + col] : 0.f);
    }
    *reinterpret_cast<uint2*>(out + (size_t)gtid * 8) = *reinterpret_cast<const uint2*>(v);
}

#define MFMA_ALL(aa, bb)                                                         \
    {                                                                            \
        __builtin_amdgcn_s_setprio(1);                                           \
        _Pragma("unroll")                                                        \
        for (int g = 0; g < 4; ++g)                                              \
            _Pragma("unroll")                                                    \
            for (int mt = 0; mt < 4; ++mt)                                       \
                acc[g][mt] = __builtin_amdgcn_mfma_f32_16x16x32_fp8_fp8(         \
                    aa[mt], bb[g], acc[g][mt], 0, 0, 0);                         \
        __builtin_amdgcn_s_setprio(0);                                           \
    }

// ---------------- one LSTM layer-step (identical math to round-8 kernel) ----
__device__ __forceinline__ void lstm_substep(
    const unsigned char* __restrict__ A0p, int kb0,
    const unsigned char* __restrict__ Wp0,
    const unsigned char* __restrict__ A1p, int kb1,
    const unsigned char* __restrict__ Wp1,
    const float* __restrict__ bias,
    float* __restrict__ c,
    unsigned char* __restrict__ h_out,
    float (*zs)[64][16],
    int ut, int mh, int tid, int lane, int kq)
{
    const unsigned char* a0 = A0p + ((size_t)(mh * 4) * kb0) * 512 + lane * 8;
    const unsigned char* a1 = A1p + ((size_t)(mh * 4) * kb1) * 512 + lane * 8;
    const unsigned char* w0 = Wp0 + ((size_t)(ut * kb0) * 4) * 512 + lane * 8;
    const unsigned char* w1 = Wp1 + ((size_t)(ut * kb1) * 4) * 512 + lane * 8;

    f32x4 acc[4][4];   // [gate][mt]
#pragma unroll
    for (int g = 0; g < 4; ++g)
#pragma unroll
        for (int mt = 0; mt < 4; ++mt) acc[g][mt] = f32x4{0.f, 0.f, 0.f, 0.f};

    auto LOAD = [&](int i, long* a, long* bfr) {
        if (i < kb0) {
#pragma unroll
            for (int mt = 0; mt < 4; ++mt)
                a[mt] = *reinterpret_cast<const long*>(a0 + (size_t)(mt * kb0 + i) * 512);
#pragma unroll
            for (int g = 0; g < 4; ++g)
                bfr[g] = *reinterpret_cast<const long*>(w0 + (size_t)(i * 4 + g) * 512);
        } else {
            int ii = i - kb0;
#pragma unroll
            for (int mt = 0; mt < 4; ++mt)
                a[mt] = *reinterpret_cast<const long*>(a1 + (size_t)(mt * kb1 + ii) * 512);
#pragma unroll
            for (int g = 0; g < 4; ++g)
                bfr[g] = *reinterpret_cast<const long*>(w1 + (size_t)(ii * 4 + g) * 512);
        }
    };

    const int KBt = kb0 + kb1;        // 72 or 128 (divisible by 8)
    const int KBq = KBt >> 3;
    const int beg = kq * KBq;
    const int end = beg + KBq;

    long aA[4], bA[4], aB[4], bB[4];
    int i = beg;
    LOAD(i, aA, bA);
    for (; i + 1 < end; i += 2) {
        LOAD(i + 1, aB, bB);
        MFMA_ALL(aA, bA);
        if (i + 2 < end) LOAD(i + 2, aA, bA);
        MFMA_ALL(aB, bB);
    }
    if (i < end) MFMA_ALL(aA, bA);

    // kq-partial reduction, one gate at a time through the 32KB LDS buffer
    const int lr = tid >> 3;          // 0..63
    const int u0 = (tid & 7) * 2;     // 0,2,..,14
    float zg2[4][2];
#pragma unroll
    for (int g = 0; g < 4; ++g) {
        __syncthreads();
#pragma unroll
        for (int mt = 0; mt < 4; ++mt)
#pragma unroll
            for (int r = 0; r < 4; ++r)
                zs[kq][mt * 16 + (lane >> 4) * 4 + r][lane & 15] = acc[g][mt][r];
        __syncthreads();
        float s0 = 0.f, s1 = 0.f;
#pragma unroll
        for (int w8 = 0; w8 < 8; ++w8) {
            s0 += zs[w8][lr][u0];
            s1 += zs[w8][lr][u0 + 1];
        }
        zg2[g][0] = s0;
        zg2[g][1] = s1;
    }

    // fused cell update for 2 units (rescale acc by 1/(SA*SB) before bias)
    const int grow = mh * 64 + lr;
    const int unit = ut * 16 + u0;
    const float2 bi  = *reinterpret_cast<const float2*>(&bias[unit]);
    const float2 bfv = *reinterpret_cast<const float2*>(&bias[U_ + unit]);
    const float2 bgv = *reinterpret_cast<const float2*>(&bias[2 * U_ + unit]);
    const float2 bov = *reinterpret_cast<const float2*>(&bias[3 * U_ + unit]);
    float2 cv = *reinterpret_cast<float2*>(&c[(size_t)grow * U_ + unit]);

    float cn[2];
    unsigned char hv[2];
#pragma unroll
    for (int e = 0; e < 2; ++e) {
        float zi = zg2[0][e] * INV_SASB_ + (e ? bi.y : bi.x);
        float zf = zg2[1][e] * INV_SASB_ + (e ? bfv.y : bfv.x);
        float zg = zg2[2][e] * INV_SASB_ + (e ? bgv.y : bgv.x);
        float zo = zg2[3][e] * INV_SASB_ + (e ? bov.y : bov.x);
        float si = 1.f / (1.f + __expf(-zi));
        float sf = 1.f / (1.f + __expf(-zf));
        float so = 1.f / (1.f + __expf(-zo));
        float tg = tanhf(zg);
        float cc = sf * (e ? cv.y : cv.x) + si * tg;
        cn[e] = cc;
        hv[e] = f2fp8(SA_ * so * tanhf(cc));
    }
    *reinterpret_cast<float2*>(&c[(size_t)grow * U_ + unit]) = make_float2(cn[0], cn[1]);

    const int mt = lr >> 4;
    const int cl = lr & 15;
    const int fi = (mh * 4 + mt) * 64 + (unit >> 5);
    const int lp = ((unit >> 3) & 3) * 16 + cl;
    uchar2 hv2; hv2.x = hv[0]; hv2.y = hv[1];
    *reinterpret_cast<uchar2*>(&h_out[(size_t)fi * 512 + lp * 8 + (unit & 7)]) = hv2;
}

// ---------------- persistent kernel: all 80 timesteps, both layers ----------
// grid 256 (1 block/CU), 512 thr. Phase k = { L1(k), L0(k+1) }, one grid sync
// per phase (L1(k) and L0(k+1) are independent, both consume h0(k)).
__global__ __launch_bounds__(512)
void lstm_persistent(const unsigned char* __restrict__ Xp,
                     const unsigned char* __restrict__ W0p,
                     const unsigned char* __restrict__ U0p,
                     const unsigned char* __restrict__ W1p,
                     const unsigned char* __restrict__ U1p,
                     const float* __restrict__ b0,
                     const float* __restrict__ b1,
                     float* __restrict__ c0, float* __restrict__ c1,
                     unsigned char* __restrict__ h0a, unsigned char* __restrict__ h0b,
                     unsigned char* __restrict__ h1a, unsigned char* __restrict__ h1b) {
    cg::grid_group grid = cg::this_grid();
    __shared__ float zs[8][64][16];   // 32 KB

    const int tid  = threadIdx.x;
    const int lane = tid & 63;
    const int kq   = tid >> 6;     // 0..7
    const int b    = blockIdx.x;
    const int s    = b >> 3;
    const int ut   = (b & 7) * 16 + (s >> 1);   // XCD-aware: xcd owns 16 ut
    const int mh   = s & 1;

    // prologue: L0(t=0): x(0) + h0a(=0) -> h0b
    lstm_substep(Xp, 8, W0p, h0a, 64, U0p, b0, c0, h0b, zs, ut, mh, tid, lane, kq);
    grid.sync();

    for (int k = 0; k < T_; ++k) {
        // h0(t) lives in (t&1)?h0a:h0b ; h1(t) in (t&1)?h1a:h1b
        const unsigned char* h0cur = (k & 1) ? h0a : h0b;
        const unsigned char* h1in  = (k & 1) ? h1b : h1a;
        unsigned char*       h1out = (k & 1) ? h1a : h1b;

        // L1(k): h0(k) (kb0=64, W1p) + h1(k-1) (kb1=64, U1p) -> h1(k)
        lstm_substep(h0cur, 64, W1p, h1in, 64, U1p, b1, c1, h1out,
                     zs, ut, mh, tid, lane, kq);

        if (k + 1 < T_) {
            // L0(k+1): x(k+1) (kb0=8, W0p) + h0(k) (kb1=64, U0p) -> h0(k+1)
            unsigned char* h0out = ((k + 1) & 1) ? h0a : h0b;
            lstm_substep(Xp + (size_t)(k + 1) * 8 * 8 * 512, 8, W0p,
                         h0cur, 64, U0p, b0, c0, h0out,
                         zs, ut, mh, tid, lane, kq);
        }
        grid.sync();
    }
}

// ---------------- head: y = relu((h1 @ Wd)/512 + bd); fp8 operands ----------
__global__ __launch_bounds__(256)
void head_mfma(const unsigned char* __restrict__ h1p,
               const unsigned char* __restrict__ Wdp,
               const float* __restrict__ bd, float* __restrict__ y) {
    const int lane = threadIdx.x & 63;
    const int w    = threadIdx.x >> 6;  // k-split wave
    const int ut   = blockIdx.x & 127;
    const int mh   = blockIdx.x >> 7;

    const unsigned char* ap = h1p + ((size_t)(mh * 4) * 64) * 512 + lane * 8;
    const unsigned char* wp = Wdp + (size_t)(ut * 64 + w * 16) * 512 + lane * 8;

    f32x4 acc[4];
#pragma unroll
    for (int mt = 0; mt < 4; ++mt) acc[mt] = f32x4{0.f, 0.f, 0.f, 0.f};

    auto LOADH = [&](int i, long* a, long& b) {
        b = *reinterpret_cast<const long*>(wp + (size_t)i * 512);
        int kb = w * 16 + i;
#pragma unroll
        for (int mt = 0; mt < 4; ++mt)
            a[mt] = *reinterpret_cast<const long*>(ap + (size_t)(mt * 64 + kb) * 512);
    };

    long aA[4], bA, aB[4], bB;
    LOADH(0, aA, bA);
    for (int i = 0; i < 16; i += 2) {
        LOADH(i + 1, aB, bB);
#pragma unroll
        for (int mt = 0; mt < 4; ++mt)
            acc[mt] = __builtin_amdgcn_mfma_f32_16x16x32_fp8_fp8(aA[mt], bA, acc[mt], 0, 0, 0);
        if (i + 2 < 16) LOADH(i + 2, aA, bA);
#pragma unroll
        for (int mt = 0; mt < 4; ++mt)
            acc[mt] = __builtin_amdgcn_mfma_f32_16x16x32_fp8_fp8(aB[mt], bB, acc[mt], 0, 0, 0);
    }

    __shared__ float zs[4][64][16];
#pragma unroll
    for (int mt = 0; mt < 4; ++mt)
#pragma unroll
        for (int r = 0; r < 4; ++r)
            zs[w][mt * 16 + (lane >> 4) * 4 + r][lane & 15] = acc[mt][r];
    __syncthreads();

    const int tid = threadIdx.x;
    const int lr  = tid >> 2;
    const int u4  = (tid & 3) * 4;
    const int grow = mh * 64 + lr;
    const int gu   = ut * 16 + u4;

    float4 s0 = *reinterpret_cast<float4*>(&zs[0][lr][u4]);
    float4 s1 = *reinterpret_cast<float4*>(&zs[1][lr][u4]);
    float4 s2 = *reinterpret_cast<float4*>(&zs[2][lr][u4]);
    float4 s3 = *reinterpret_cast<float4*>(&zs[3][lr][u4]);
    const float4 bb = *reinterpret_cast<const float4*>(&bd[gu]);
    float4 r;
    r.x = (s0.x + s1.x + s2.x + s3.x) * INV_SASB_ + bb.x;
    r.y = (s0.y + s1.y + s2.y + s3.y) * INV_SASB_ + bb.y;
    r.z = (s0.z + s1.z + s2.z + s3.z) * INV_SASB_ + bb.z;
    r.w = (s0.w + s1.w + s2.w + s3.w) * INV_SASB_ + bb.w;
    r.x = r.x > 0.f ? r.x : 0.f;
    r.y = r.y > 0.f ? r.y : 0.f;
    r.z = r.z > 0.f ? r.z : 0.f;
    r.w = r.w > 0.f ? r.w : 0.f;
    *reinterpret_cast<float4*>(&y[(size_t)grow * U_ + gu]) = r;
}

// ---------------- out[b] = sigmoid(y[b,:] @ Wo + bo) ----------------
__global__ __launch_bounds__(256)
void head2(const float* __restrict__ y, const float* __restrict__ Wo,
           const float* __restrict__ bo, float* __restrict__ out) {
    __shared__ float red[256];
    const int b = blockIdx.x;
    const int tid = threadIdx.x;
    float s = 0.f;
    for (int u = tid; u < U_; u += 256) s += y[(size_t)b * U_ + u] * Wo[u];
    red[tid] = s;
    __syncthreads();
    for (int off = 128; off > 0; off >>= 1) {
        if (tid < off) red[tid] += red[tid + off];
        __syncthreads();
    }
    if (tid == 0) out[b] = 1.f / (1.f + __expf(-(red[0] + bo[0])));
}

extern "C" void kernel_launch(void* const* d_in, const int* in_sizes, int n_in,
                              void* d_out, int out_size, void* d_ws, size_t ws_size,
                              hipStream_t stream) {
    const int*   tokens = (const int*)  d_in[0];
    const float* emb    = (const float*)d_in[1];
    const float* W0     = (const float*)d_in[2];
    const float* U0     = (const float*)d_in[3];
    const float* b0     = (const float*)d_in[4];
    const float* W1     = (const float*)d_in[5];
    const float* U1     = (const float*)d_in[6];
    const float* b1     = (const float*)d_in[7];
    const float* Wd     = (const float*)d_in[8];
    const float* bd     = (const float*)d_in[9];
    const float* Wo     = (const float*)d_in[10];
    const float* bo     = (const float*)d_in[11];

    // ws layout (bytes); total ~62 MB
    char* base = (char*)d_ws;
    unsigned char* h0a = (unsigned char*)(base + 0);         // 256 KB (packed fp8)
    unsigned char* h1a = (unsigned char*)(base + 262144);    // 256 KB
    float*         c0  = (float*)        (base + 524288);    // 1 MB
    float*         c1  = (float*)        (base + 1572864);   // 1 MB
    unsigned char* h0b = (unsigned char*)(base + 2621440);   // 256 KB
    unsigned char* h1b = (unsigned char*)(base + 2883584);   // 256 KB
    unsigned char* Xp  = (unsigned char*)(base + 3145728);   // 2.62 MB
    float*         yb  = (float*)        (base + 3145728);   // overlays Xp (dead by head)
    unsigned char* W0p = (unsigned char*)(base + 5767168);   // 2 MB
    unsigned char* U0p = (unsigned char*)(base + 7864320);   // 16 MB
    unsigned char* W1p = (unsigned char*)(base + 24641536);  // 16 MB
    unsigned char* U1p = (unsigned char*)(base + 41418752);  // 16 MB
    unsigned char* Wdp = (unsigned char*)(base + 58195968);  // 4 MB

    // zero h0a, h1a, c0, c1 (contiguous 2.56 MB)
    hipMemsetAsync(d_ws, 0, 2621440, stream);

    embed_pack<<<(T_ * 8 * 8 * 64 + 255) / 256, 256, 0, stream>>>(tokens, emb, Xp);
    pack_w<<<1024, 256, 0, stream>>>(W0, E_, G4_, 4, 8,  W0p);
    pack_w<<<8192, 256, 0, stream>>>(U0, U_, G4_, 4, 64, U0p);
    pack_w<<<8192, 256, 0, stream>>>(W1, U_, G4_, 4, 64, W1p);
    pack_w<<<8192, 256, 0, stream>>>(U1, U_, G4_, 4, 64, U1p);
    pack_w<<<2048, 256, 0, stream>>>(Wd, U_, U_,  1, 64, Wdp);

    void* params[13];
    params[0]  = (void*)&Xp;
    params[1]  = (void*)&W0p;
    params[2]  = (void*)&U0p;
    params[3]  = (void*)&W1p;
    params[4]  = (void*)&U1p;
    params[5]  = (void*)&b0;
    params[6]  = (void*)&b1;
    params[7]  = (void*)&c0;
    params[8]  = (void*)&c1;
    params[9]  = (void*)&h0a;
    params[10] = (void*)&h0b;
    params[11] = (void*)&h1a;
    params[12] = (void*)&h1b;
    hipLaunchCooperativeKernel((void*)lstm_persistent, dim3(256), dim3(512),
                               params, 0, stream);

    // t=79 (odd) wrote h1a
    head_mfma<<<256, 256, 0, stream>>>(h1a, Wdp, bd, yb);
    head2<<<B_, 256, 0, stream>>>(yb, Wo, bo, (float*)d_out);
}

// Round 10
// 2066.965 us; speedup vs baseline: 1.8800x; 1.8800x over previous
//
#include <hip/hip_runtime.h>
#include <hip/hip_bf16.h>
#include <hip/hip_fp8.h>
#include <cstdint>

#define B_   128
#define T_   80
#define E_   100
#define U_   2048
#define G4_  8192

// scales: A-side (x,h) x16, B-side (weights) x32; acc * 1/512 restores z
#define SA_   16.0f
#define SB_   32.0f
#define INV_SASB_ (1.0f / 512.0f)

typedef __attribute__((ext_vector_type(4))) float f32x4;

__device__ __forceinline__ unsigned char f2fp8(float x) {
    __hip_fp8_e4m3 q(x);
    return q.__x;
}

// ---------------- embedding -> A-fragment-packed fp8 X (kb0 = 8 frags) -----
__global__ __launch_bounds__(256)
void embed_pack(const int* __restrict__ tokens, const float* __restrict__ emb,
                unsigned char* __restrict__ Xp) {
    int gtid = blockIdx.x * 256 + threadIdx.x;   // one 8-byte chunk each
    if (gtid >= T_ * 8 * 8 * 64) return;
    int lane = gtid & 63;
    int rest = gtid >> 6;
    int i    = rest & 7;  rest >>= 3;
    int mtg  = rest & 7;
    int t    = rest >> 3;
    int row  = (mtg >> 2) * 64 + (mtg & 3) * 16 + (lane & 15);
    int k0   = i * 32 + (lane >> 4) * 8;
    const float* erow = emb + (size_t)tokens[row * T_ + t] * E_;
    unsigned char v[8];
#pragma unroll
    for (int j = 0; j < 8; ++j) {
        int e = k0 + j;
        v[j] = f2fp8(e < E_ ? SA_ * erow[e] : 0.f);
    }
    *reinterpret_cast<uint2*>(Xp + (size_t)gtid * 8) = *reinterpret_cast<const uint2*>(v);
}

// ---------------- fused pack of all 5 weight matrices -----------------------
// segments (by blockIdx.x): [0,8192) U0 | [8192,16384) W1 | [16384,24576) U1
//                           [24576,25600) W0 | [25600,27648) Wd
__global__ __launch_bounds__(256)
void pack_all(const float* __restrict__ W0, const float* __restrict__ U0,
              const float* __restrict__ W1, const float* __restrict__ U1,
              const float* __restrict__ Wd,
              unsigned char* __restrict__ W0p, unsigned char* __restrict__ U0p,
              unsigned char* __restrict__ W1p, unsigned char* __restrict__ U1p,
              unsigned char* __restrict__ Wdp) {
    int blk = blockIdx.x;
    const float* W; int K, Ncols, NG, KB; unsigned char* out; int lb;
    if (blk < 8192)       { W = U0; K = U_; Ncols = G4_; NG = 4; KB = 64; out = U0p; lb = blk; }
    else if (blk < 16384) { W = W1; K = U_; Ncols = G4_; NG = 4; KB = 64; out = W1p; lb = blk - 8192; }
    else if (blk < 24576) { W = U1; K = U_; Ncols = G4_; NG = 4; KB = 64; out = U1p; lb = blk - 16384; }
    else if (blk < 25600) { W = W0; K = E_; Ncols = G4_; NG = 4; KB = 8;  out = W0p; lb = blk - 24576; }
    else                  { W = Wd; K = U_; Ncols = U_;  NG = 1; KB = 64; out = Wdp; lb = blk - 25600; }

    int gtid = lb * 256 + threadIdx.x;
    int lane = gtid & 63;
    int rest = gtid >> 6;
    int g = rest % NG; rest /= NG;
    int i = rest % KB;
    int ut = rest / KB;
    if (ut >= U_ / 16) return;
    int col = g * U_ + ut * 16 + (lane & 15);
    int k0 = i * 32 + (lane >> 4) * 8;
    unsigned char v[8];
#pragma unroll
    for (int j = 0; j < 8; ++j) {
        int k = k0 + j;
        v[j] = f2fp8(k < K ? SB_ * W[(size_t)k * Ncols + col] : 0.f);
    }
    *reinterpret_cast<uint2*>(out + (size_t)gtid * 8) = *reinterpret_cast<const uint2*>(v);
}

#define MFMA_ALL(aa, bb)                                                         \
    {                                                                            \
        __builtin_amdgcn_s_setprio(1);                                           \
        _Pragma("unroll")                                                        \
        for (int g = 0; g < 4; ++g)                                              \
            _Pragma("unroll")                                                    \
            for (int mt = 0; mt < 4; ++mt)                                       \
                acc[g][mt] = __builtin_amdgcn_mfma_f32_16x16x32_fp8_fp8(         \
                    aa[mt], bb[g], acc[g][mt], 0, 0, 0);                         \
        __builtin_amdgcn_s_setprio(0);                                           \
    }

// ---------------- one LSTM layer-step (round-8 math; padded LDS) ------------
__device__ __forceinline__ void lstm_substep(
    const unsigned char* __restrict__ A0p, int kb0,
    const unsigned char* __restrict__ Wp0,
    const unsigned char* __restrict__ A1p, int kb1,
    const unsigned char* __restrict__ Wp1,
    const float* __restrict__ bias,
    float* __restrict__ c,
    unsigned char* __restrict__ h_out,
    float (*zs)[64][17],
    int ut, int mh, int tid, int lane, int kq)
{
    const unsigned char* a0 = A0p + ((size_t)(mh * 4) * kb0) * 512 + lane * 8;
    const unsigned char* a1 = A1p + ((size_t)(mh * 4) * kb1) * 512 + lane * 8;
    const unsigned char* w0 = Wp0 + ((size_t)(ut * kb0) * 4) * 512 + lane * 8;
    const unsigned char* w1 = Wp1 + ((size_t)(ut * kb1) * 4) * 512 + lane * 8;

    f32x4 acc[4][4];   // [gate][mt]
#pragma unroll
    for (int g = 0; g < 4; ++g)
#pragma unroll
        for (int mt = 0; mt < 4; ++mt) acc[g][mt] = f32x4{0.f, 0.f, 0.f, 0.f};

    auto LOAD = [&](int i, long* a, long* bfr) {
        if (i < kb0) {
#pragma unroll
            for (int mt = 0; mt < 4; ++mt)
                a[mt] = *reinterpret_cast<const long*>(a0 + (size_t)(mt * kb0 + i) * 512);
#pragma unroll
            for (int g = 0; g < 4; ++g)
                bfr[g] = *reinterpret_cast<const long*>(w0 + (size_t)(i * 4 + g) * 512);
        } else {
            int ii = i - kb0;
#pragma unroll
            for (int mt = 0; mt < 4; ++mt)
                a[mt] = *reinterpret_cast<const long*>(a1 + (size_t)(mt * kb1 + ii) * 512);
#pragma unroll
            for (int g = 0; g < 4; ++g)
                bfr[g] = *reinterpret_cast<const long*>(w1 + (size_t)(ii * 4 + g) * 512);
        }
    };

    const int KBt = kb0 + kb1;        // 72 or 128 (divisible by 8)
    const int KBq = KBt >> 3;
    const int beg = kq * KBq;
    const int end = beg + KBq;

    long aA[4], bA[4], aB[4], bB[4];
    int i = beg;
    LOAD(i, aA, bA);
    for (; i + 1 < end; i += 2) {
        LOAD(i + 1, aB, bB);
        MFMA_ALL(aA, bA);
        if (i + 2 < end) LOAD(i + 2, aA, bA);
        MFMA_ALL(aB, bB);
    }
    if (i < end) MFMA_ALL(aA, bA);

    // kq-partial reduction, one gate at a time (zs padded: stride 17 floats)
    const int lr = tid >> 3;          // 0..63
    const int u0 = (tid & 7) * 2;     // 0,2,..,14
    float zg2[4][2];
#pragma unroll
    for (int g = 0; g < 4; ++g) {
        __syncthreads();
#pragma unroll
        for (int mt = 0; mt < 4; ++mt)
#pragma unroll
            for (int r = 0; r < 4; ++r)
                zs[kq][mt * 16 + (lane >> 4) * 4 + r][lane & 15] = acc[g][mt][r];
        __syncthreads();
        float s0 = 0.f, s1 = 0.f;
#pragma unroll
        for (int w8 = 0; w8 < 8; ++w8) {
            s0 += zs[w8][lr][u0];
            s1 += zs[w8][lr][u0 + 1];
        }
        zg2[g][0] = s0;
        zg2[g][1] = s1;
    }

    // fused cell update for 2 units (rescale acc by 1/(SA*SB) before bias)
    const int grow = mh * 64 + lr;
    const int unit = ut * 16 + u0;
    const float2 bi  = *reinterpret_cast<const float2*>(&bias[unit]);
    const float2 bfv = *reinterpret_cast<const float2*>(&bias[U_ + unit]);
    const float2 bgv = *reinterpret_cast<const float2*>(&bias[2 * U_ + unit]);
    const float2 bov = *reinterpret_cast<const float2*>(&bias[3 * U_ + unit]);
    float2 cv = *reinterpret_cast<float2*>(&c[(size_t)grow * U_ + unit]);

    float cn[2];
    unsigned char hv[2];
#pragma unroll
    for (int e = 0; e < 2; ++e) {
        float zi = zg2[0][e] * INV_SASB_ + (e ? bi.y : bi.x);
        float zf = zg2[1][e] * INV_SASB_ + (e ? bfv.y : bfv.x);
        float zg = zg2[2][e] * INV_SASB_ + (e ? bgv.y : bgv.x);
        float zo = zg2[3][e] * INV_SASB_ + (e ? bov.y : bov.x);
        float si = 1.f / (1.f + __expf(-zi));
        float sf = 1.f / (1.f + __expf(-zf));
        float so = 1.f / (1.f + __expf(-zo));
        float tg = tanhf(zg);
        float cc = sf * (e ? cv.y : cv.x) + si * tg;
        cn[e] = cc;
        hv[e] = f2fp8(SA_ * so * tanhf(cc));
    }
    *reinterpret_cast<float2*>(&c[(size_t)grow * U_ + unit]) = make_float2(cn[0], cn[1]);

    const int mt = lr >> 4;
    const int cl = lr & 15;
    const int fi = (mh * 4 + mt) * 64 + (unit >> 5);
    const int lp = ((unit >> 3) & 3) * 16 + cl;
    uchar2 hv2; hv2.x = hv[0]; hv2.y = hv[1];
    *reinterpret_cast<uchar2*>(&h_out[(size_t)fi * 512 + lp * 8 + (unit & 7)]) = hv2;
}

// ---------------- prologue: L0(0) only, grid 256 ----------------------------
__global__ __launch_bounds__(512)
void lstm_l0_first(const unsigned char* __restrict__ Xp,
                   const unsigned char* __restrict__ W0p,
                   const unsigned char* __restrict__ U0p,
                   const float* __restrict__ b0,
                   float* __restrict__ c0,
                   const unsigned char* __restrict__ h0zero,
                   unsigned char* __restrict__ h0out) {
    __shared__ float zs[8][64][17];
    const int tid  = threadIdx.x;
    const int lane = tid & 63;
    const int kq   = tid >> 6;
    const int b    = blockIdx.x;
    const int s    = b >> 3;
    const int ut   = (b & 7) * 16 + (s >> 1);
    const int mh   = s & 1;
    lstm_substep(Xp, 8, W0p, h0zero, 64, U0p, b0, c0, h0out,
                 zs, ut, mh, tid, lane, kq);
}

// ---------------- fused pair: blocks split between L1(k) and L0(k+1) --------
// grid 512. xcd = b&7; w = b>>3 (0..63); role = w&1; q = w>>1 (0..31);
// ut = xcd*16 + (q>>1); mh = q&1.  Each (role, ut, mh) covered exactly once.
__global__ __launch_bounds__(512)
void lstm_fused_pair(const unsigned char* __restrict__ Xp,
                     const unsigned char* __restrict__ W0p,
                     const unsigned char* __restrict__ U0p,
                     const unsigned char* __restrict__ W1p,
                     const unsigned char* __restrict__ U1p,
                     const float* __restrict__ b0,
                     const float* __restrict__ b1,
                     float* __restrict__ c0, float* __restrict__ c1,
                     unsigned char* __restrict__ h0a, unsigned char* __restrict__ h0b,
                     unsigned char* __restrict__ h1a, unsigned char* __restrict__ h1b,
                     int k) {
    __shared__ float zs[8][64][17];
    const int tid  = threadIdx.x;
    const int lane = tid & 63;
    const int kq   = tid >> 6;
    const int b    = blockIdx.x;
    const int xcd  = b & 7;
    const int w    = b >> 3;
    const int role = w & 1;
    const int q    = w >> 1;
    const int ut   = xcd * 16 + (q >> 1);
    const int mh   = q & 1;

    const unsigned char* h0cur = (k & 1) ? h0a : h0b;

    if (role == 0) {
        // L1(k): h0(k) + h1(k-1) -> h1(k)
        const unsigned char* h1in  = (k & 1) ? h1b : h1a;
        unsigned char*       h1out = (k & 1) ? h1a : h1b;
        lstm_substep(h0cur, 64, W1p, h1in, 64, U1p, b1, c1, h1out,
                     zs, ut, mh, tid, lane, kq);
    } else {
        if (k + 1 < T_) {
            // L0(k+1): x(k+1) + h0(k) -> h0(k+1)
            unsigned char* h0out = ((k + 1) & 1) ? h0a : h0b;
            lstm_substep(Xp + (size_t)(k + 1) * 8 * 8 * 512, 8, W0p,
                         h0cur, 64, U0p, b0, c0, h0out,
                         zs, ut, mh, tid, lane, kq);
        }
    }
}

// ---------------- head: y = relu((h1 @ Wd)/512 + bd); fp8 operands ----------
__global__ __launch_bounds__(256)
void head_mfma(const unsigned char* __restrict__ h1p,
               const unsigned char* __restrict__ Wdp,
               const float* __restrict__ bd, float* __restrict__ y) {
    const int lane = threadIdx.x & 63;
    const int w    = threadIdx.x >> 6;  // k-split wave
    const int ut   = blockIdx.x & 127;
    const int mh   = blockIdx.x >> 7;

    const unsigned char* ap = h1p + ((size_t)(mh * 4) * 64) * 512 + lane * 8;
    const unsigned char* wp = Wdp + (size_t)(ut * 64 + w * 16) * 512 + lane * 8;

    f32x4 acc[4];
#pragma unroll
    for (int mt = 0; mt < 4; ++mt) acc[mt] = f32x4{0.f, 0.f, 0.f, 0.f};

    auto LOADH = [&](int i, long* a, long& b) {
        b = *reinterpret_cast<const long*>(wp + (size_t)i * 512);
        int kb = w * 16 + i;
#pragma unroll
        for (int mt = 0; mt < 4; ++mt)
            a[mt] = *reinterpret_cast<const long*>(ap + (size_t)(mt * 64 + kb) * 512);
    };

    long aA[4], bA, aB[4], bB;
    LOADH(0, aA, bA);
    for (int i = 0; i < 16; i += 2) {
        LOADH(i + 1, aB, bB);
#pragma unroll
        for (int mt = 0; mt < 4; ++mt)
            acc[mt] = __builtin_amdgcn_mfma_f32_16x16x32_fp8_fp8(aA[mt], bA, acc[mt], 0, 0, 0);
        if (i + 2 < 16) LOADH(i + 2, aA, bA);
#pragma unroll
        for (int mt = 0; mt < 4; ++mt)
            acc[mt] = __builtin_amdgcn_mfma_f32_16x16x32_fp8_fp8(aB[mt], bB, acc[mt], 0, 0, 0);
    }

    __shared__ float zs[4][64][17];
#pragma unroll
    for (int mt = 0; mt < 4; ++mt)
#pragma unroll
        for (int r = 0; r < 4; ++r)
            zs[w][mt * 16 + (lane >> 4) * 4 + r][lane & 15] = acc[mt][r];
    __syncthreads();

    const int tid = threadIdx.x;
    const int lr  = tid >> 2;
    const int u4  = (tid & 3) * 4;
    const int grow = mh * 64 + lr;
    const int gu   = ut * 16 + u4;

    float s0, s1, s2, s3;
    float4 r;
    float* rr = &r.x;
#pragma unroll
    for (int e = 0; e < 4; ++e) {
        s0 = zs[0][lr][u4 + e]; s1 = zs[1][lr][u4 + e];
        s2 = zs[2][lr][u4 + e]; s3 = zs[3][lr][u4 + e];
        float v = (s0 + s1 + s2 + s3) * INV_SASB_ + bd[gu + e];
        rr[e] = v > 0.f ? v : 0.f;
    }
    *reinterpret_cast<float4*>(&y[(size_t)grow * U_ + gu]) = r;
}

// ---------------- out[b] = sigmoid(y[b,:] @ Wo + bo) ----------------
__global__ __launch_bounds__(256)
void head2(const float* __restrict__ y, const float* __restrict__ Wo,
           const float* __restrict__ bo, float* __restrict__ out) {
    __shared__ float red[256];
    const int b = blockIdx.x;
    const int tid = threadIdx.x;
    float s = 0.f;
    for (int u = tid; u < U_; u += 256) s += y[(size_t)b * U_ + u] * Wo[u];
    red[tid] = s;
    __syncthreads();
    for (int off = 128; off > 0; off >>= 1) {
        if (tid < off) red[tid] += red[tid + off];
        __syncthreads();
    }
    if (tid == 0) out[b] = 1.f / (1.f + __expf(-(red[0] + bo[0])));
}

extern "C" void kernel_launch(void* const* d_in, const int* in_sizes, int n_in,
                              void* d_out, int out_size, void* d_ws, size_t ws_size,
                              hipStream_t stream) {
    const int*   tokens = (const int*)  d_in[0];
    const float* emb    = (const float*)d_in[1];
    const float* W0     = (const float*)d_in[2];
    const float* U0     = (const float*)d_in[3];
    const float* b0     = (const float*)d_in[4];
    const float* W1     = (const float*)d_in[5];
    const float* U1     = (const float*)d_in[6];
    const float* b1     = (const float*)d_in[7];
    const float* Wd     = (const float*)d_in[8];
    const float* bd     = (const float*)d_in[9];
    const float* Wo     = (const float*)d_in[10];
    const float* bo     = (const float*)d_in[11];

    // ws layout (bytes); total ~62 MB
    char* base = (char*)d_ws;
    unsigned char* h0a = (unsigned char*)(base + 0);         // 256 KB (packed fp8)
    unsigned char* h1a = (unsigned char*)(base + 262144);    // 256 KB
    float*         c0  = (float*)        (base + 524288);    // 1 MB
    float*         c1  = (float*)        (base + 1572864);   // 1 MB
    unsigned char* h0b = (unsigned char*)(base + 2621440);   // 256 KB
    unsigned char* h1b = (unsigned char*)(base + 2883584);   // 256 KB
    unsigned char* Xp  = (unsigned char*)(base + 3145728);   // 2.62 MB
    float*         yb  = (float*)        (base + 3145728);   // overlays Xp (dead by head)
    unsigned char* W0p = (unsigned char*)(base + 5767168);   // 2 MB
    unsigned char* U0p = (unsigned char*)(base + 7864320);   // 16 MB
    unsigned char* W1p = (unsigned char*)(base + 24641536);  // 16 MB
    unsigned char* U1p = (unsigned char*)(base + 41418752);  // 16 MB
    unsigned char* Wdp = (unsigned char*)(base + 58195968);  // 4 MB

    // zero h0a, h1a, c0, c1 (contiguous 2.56 MB)
    hipMemsetAsync(d_ws, 0, 2621440, stream);

    embed_pack<<<(T_ * 8 * 8 * 64 + 255) / 256, 256, 0, stream>>>(tokens, emb, Xp);
    pack_all<<<27648, 256, 0, stream>>>(W0, U0, W1, U1, Wd,
                                        W0p, U0p, W1p, U1p, Wdp);

    // prologue: L0(0): x(0) + h0a(=0) -> h0b
    lstm_l0_first<<<256, 512, 0, stream>>>(Xp, W0p, U0p, b0, c0, h0a, h0b);

    // fused loop: each dispatch k does L1(k) and L0(k+1)
    for (int k = 0; k < T_; ++k) {
        lstm_fused_pair<<<512, 512, 0, stream>>>(Xp, W0p, U0p, W1p, U1p,
                                                 b0, b1, c0, c1,
                                                 h0a, h0b, h1a, h1b, k);
    }
    // t=79 (odd) wrote h1a
    head_mfma<<<256, 256, 0, stream>>>(h1a, Wdp, bd, yb);
    head2<<<B_, 256, 0, stream>>>(yb, Wo, bo, (float*)d_out);
}

// Round 11
// 1804.517 us; speedup vs baseline: 2.1534x; 1.1454x over previous
//
#include <hip/hip_runtime.h>
#include <hip/hip_bf16.h>
#include <hip/hip_fp8.h>
#include <cstdint>

#define B_   128
#define T_   80
#define E_   100
#define U_   2048
#define G4_  8192

// scales: A-side (x,h) x16, B-side (weights) x32; acc * 1/512 restores z
#define SA_   16.0f
#define SB_   32.0f
#define INV_SASB_ (1.0f / 512.0f)

typedef __attribute__((ext_vector_type(4))) float f32x4;

__device__ __forceinline__ unsigned char f2fp8(float x) {
    __hip_fp8_e4m3 q(x);
    return q.__x;
}

// ---------------- embedding -> A-fragment-packed fp8 X (kb0 = 8 frags) -----
__global__ __launch_bounds__(256)
void embed_pack(const int* __restrict__ tokens, const float* __restrict__ emb,
                unsigned char* __restrict__ Xp) {
    int gtid = blockIdx.x * 256 + threadIdx.x;   // one 8-byte chunk each
    if (gtid >= T_ * 8 * 8 * 64) return;
    int lane = gtid & 63;
    int rest = gtid >> 6;
    int i    = rest & 7;  rest >>= 3;
    int mtg  = rest & 7;
    int t    = rest >> 3;
    int row  = (mtg >> 2) * 64 + (mtg & 3) * 16 + (lane & 15);
    int k0   = i * 32 + (lane >> 4) * 8;
    const float* erow = emb + (size_t)tokens[row * T_ + t] * E_;
    unsigned char v[8];
#pragma unroll
    for (int j = 0; j < 8; ++j) {
        int e = k0 + j;
        v[j] = f2fp8(e < E_ ? SA_ * erow[e] : 0.f);
    }
    *reinterpret_cast<uint2*>(Xp + (size_t)gtid * 8) = *reinterpret_cast<const uint2*>(v);
}

// ---------------- fused pack of all 5 weight matrices -----------------------
// segments (by blockIdx.x): [0,8192) U0 | [8192,16384) W1 | [16384,24576) U1
//                           [24576,25600) W0 | [25600,27648) Wd
__global__ __launch_bounds__(256)
void pack_all(const float* __restrict__ W0, const float* __restrict__ U0,
              const float* __restrict__ W1, const float* __restrict__ U1,
              const float* __restrict__ Wd,
              unsigned char* __restrict__ W0p, unsigned char* __restrict__ U0p,
              unsigned char* __restrict__ W1p, unsigned char* __restrict__ U1p,
              unsigned char* __restrict__ Wdp) {
    int blk = blockIdx.x;
    const float* W; int K, Ncols, NG, KB; unsigned char* out; int lb;
    if (blk < 8192)       { W = U0; K = U_; Ncols = G4_; NG = 4; KB = 64; out = U0p; lb = blk; }
    else if (blk < 16384) { W = W1; K = U_; Ncols = G4_; NG = 4; KB = 64; out = W1p; lb = blk - 8192; }
    else if (blk < 24576) { W = U1; K = U_; Ncols = G4_; NG = 4; KB = 64; out = U1p; lb = blk - 16384; }
    else if (blk < 25600) { W = W0; K = E_; Ncols = G4_; NG = 4; KB = 8;  out = W0p; lb = blk - 24576; }
    else                  { W = Wd; K = U_; Ncols = U_;  NG = 1; KB = 64; out = Wdp; lb = blk - 25600; }

    int gtid = lb * 256 + threadIdx.x;
    int lane = gtid & 63;
    int rest = gtid >> 6;
    int g = rest % NG; rest /= NG;
    int i = rest % KB;
    int ut = rest / KB;
    if (ut >= U_ / 16) return;
    int col = g * U_ + ut * 16 + (lane & 15);
    int k0 = i * 32 + (lane >> 4) * 8;
    unsigned char v[8];
#pragma unroll
    for (int j = 0; j < 8; ++j) {
        int k = k0 + j;
        v[j] = f2fp8(k < K ? SB_ * W[(size_t)k * Ncols + col] : 0.f);
    }
    *reinterpret_cast<uint2*>(out + (size_t)gtid * 8) = *reinterpret_cast<const uint2*>(v);
}

// ---------------- one LSTM layer-step: depth-3 register pipeline ------------
// Templated on fragment counts so the K-loop fully unrolls (compile-time
// buffer rotation -> registers, no scratch).
template<int KB0, int KB1>
__device__ __forceinline__ void lstm_substep(
    const unsigned char* __restrict__ A0p,
    const unsigned char* __restrict__ Wp0,
    const unsigned char* __restrict__ A1p,
    const unsigned char* __restrict__ Wp1,
    const float* __restrict__ bias,
    float* __restrict__ c,
    unsigned char* __restrict__ h_out,
    float (*zs)[64][17],
    int ut, int mh, int tid, int lane, int kq)
{
    constexpr int KBT = KB0 + KB1;    // 72 or 128
    constexpr int NIT = KBT / 8;      // 9 or 16 per wave

    const unsigned char* a0 = A0p + ((size_t)(mh * 4) * KB0) * 512 + lane * 8;
    const unsigned char* a1 = A1p + ((size_t)(mh * 4) * KB1) * 512 + lane * 8;
    const unsigned char* w0 = Wp0 + ((size_t)(ut * KB0) * 4) * 512 + lane * 8;
    const unsigned char* w1 = Wp1 + ((size_t)(ut * KB1) * 4) * 512 + lane * 8;

    const int beg = kq * NIT;

    f32x4 acc[4][4];   // [gate][mt]
#pragma unroll
    for (int g = 0; g < 4; ++g)
#pragma unroll
        for (int mt = 0; mt < 4; ++mt) acc[g][mt] = f32x4{0.f, 0.f, 0.f, 0.f};

    long Ab[3][4], Bb[3][4];    // 3-deep rotation, 48 VGPR in fp8

    auto LOAD = [&](int gi, int slot) {
        if (gi < KB0) {
#pragma unroll
            for (int mt = 0; mt < 4; ++mt)
                Ab[slot][mt] = *reinterpret_cast<const long*>(a0 + (size_t)(mt * KB0 + gi) * 512);
#pragma unroll
            for (int g = 0; g < 4; ++g)
                Bb[slot][g] = *reinterpret_cast<const long*>(w0 + (size_t)(gi * 4 + g) * 512);
        } else {
            int ii = gi - KB0;
#pragma unroll
            for (int mt = 0; mt < 4; ++mt)
                Ab[slot][mt] = *reinterpret_cast<const long*>(a1 + (size_t)(mt * KB1 + ii) * 512);
#pragma unroll
            for (int g = 0; g < 4; ++g)
                Bb[slot][g] = *reinterpret_cast<const long*>(w1 + (size_t)(ii * 4 + g) * 512);
        }
    };

    LOAD(beg, 0);
    if (NIT > 1) LOAD(beg + 1, 1);
#pragma unroll
    for (int ii = 0; ii < NIT; ++ii) {
        if (ii + 2 < NIT) LOAD(beg + ii + 2, (ii + 2) % 3);
        const int p = ii % 3;
        __builtin_amdgcn_s_setprio(1);
#pragma unroll
        for (int g = 0; g < 4; ++g)
#pragma unroll
            for (int mt = 0; mt < 4; ++mt)
                acc[g][mt] = __builtin_amdgcn_mfma_f32_16x16x32_fp8_fp8(
                    Ab[p][mt], Bb[p][g], acc[g][mt], 0, 0, 0);
        __builtin_amdgcn_s_setprio(0);
    }

    // kq-partial reduction, one gate at a time (zs padded: stride 17 floats)
    const int lr = tid >> 3;          // 0..63
    const int u0 = (tid & 7) * 2;     // 0,2,..,14
    float zg2[4][2];
#pragma unroll
    for (int g = 0; g < 4; ++g) {
        __syncthreads();
#pragma unroll
        for (int mt = 0; mt < 4; ++mt)
#pragma unroll
            for (int r = 0; r < 4; ++r)
                zs[kq][mt * 16 + (lane >> 4) * 4 + r][lane & 15] = acc[g][mt][r];
        __syncthreads();
        float s0 = 0.f, s1 = 0.f;
#pragma unroll
        for (int w8 = 0; w8 < 8; ++w8) {
            s0 += zs[w8][lr][u0];
            s1 += zs[w8][lr][u0 + 1];
        }
        zg2[g][0] = s0;
        zg2[g][1] = s1;
    }

    // fused cell update for 2 units (rescale acc by 1/(SA*SB) before bias)
    const int grow = mh * 64 + lr;
    const int unit = ut * 16 + u0;
    const float2 bi  = *reinterpret_cast<const float2*>(&bias[unit]);
    const float2 bfv = *reinterpret_cast<const float2*>(&bias[U_ + unit]);
    const float2 bgv = *reinterpret_cast<const float2*>(&bias[2 * U_ + unit]);
    const float2 bov = *reinterpret_cast<const float2*>(&bias[3 * U_ + unit]);
    float2 cv = *reinterpret_cast<float2*>(&c[(size_t)grow * U_ + unit]);

    float cn[2];
    unsigned char hv[2];
#pragma unroll
    for (int e = 0; e < 2; ++e) {
        float zi = zg2[0][e] * INV_SASB_ + (e ? bi.y : bi.x);
        float zf = zg2[1][e] * INV_SASB_ + (e ? bfv.y : bfv.x);
        float zg = zg2[2][e] * INV_SASB_ + (e ? bgv.y : bgv.x);
        float zo = zg2[3][e] * INV_SASB_ + (e ? bov.y : bov.x);
        float si = 1.f / (1.f + __expf(-zi));
        float sf = 1.f / (1.f + __expf(-zf));
        float so = 1.f / (1.f + __expf(-zo));
        float tg = tanhf(zg);
        float cc = sf * (e ? cv.y : cv.x) + si * tg;
        cn[e] = cc;
        hv[e] = f2fp8(SA_ * so * tanhf(cc));
    }
    *reinterpret_cast<float2*>(&c[(size_t)grow * U_ + unit]) = make_float2(cn[0], cn[1]);

    const int mt = lr >> 4;
    const int cl = lr & 15;
    const int fi = (mh * 4 + mt) * 64 + (unit >> 5);
    const int lp = ((unit >> 3) & 3) * 16 + cl;
    uchar2 hv2; hv2.x = hv[0]; hv2.y = hv[1];
    *reinterpret_cast<uchar2*>(&h_out[(size_t)fi * 512 + lp * 8 + (unit & 7)]) = hv2;
}

// ---------------- LSTM layer-step kernel (grid 256, XCD-swizzled) -----------
template<int KB0, int KB1>
__global__ __launch_bounds__(512)
void lstm_step_t(const unsigned char* __restrict__ A0p,
                 const unsigned char* __restrict__ Wp0,
                 const unsigned char* __restrict__ A1p,
                 const unsigned char* __restrict__ Wp1,
                 const float* __restrict__ bias,
                 float* __restrict__ c,
                 unsigned char* __restrict__ h_out) {
    __shared__ float zs[8][64][17];
    const int tid  = threadIdx.x;
    const int lane = tid & 63;
    const int kq   = tid >> 6;
    const int b    = blockIdx.x;
    const int s    = b >> 3;
    const int ut   = (b & 7) * 16 + (s >> 1);   // xcd owns 16 consecutive ut
    const int mh   = s & 1;
    lstm_substep<KB0, KB1>(A0p, Wp0, A1p, Wp1, bias, c, h_out,
                           zs, ut, mh, tid, lane, kq);
}

// ---------------- head: y = relu((h1 @ Wd)/512 + bd); fp8 operands ----------
__global__ __launch_bounds__(256)
void head_mfma(const unsigned char* __restrict__ h1p,
               const unsigned char* __restrict__ Wdp,
               const float* __restrict__ bd, float* __restrict__ y) {
    const int lane = threadIdx.x & 63;
    const int w    = threadIdx.x >> 6;  // k-split wave
    const int ut   = blockIdx.x & 127;
    const int mh   = blockIdx.x >> 7;

    const unsigned char* ap = h1p + ((size_t)(mh * 4) * 64) * 512 + lane * 8;
    const unsigned char* wp = Wdp + (size_t)(ut * 64 + w * 16) * 512 + lane * 8;

    f32x4 acc[4];
#pragma unroll
    for (int mt = 0; mt < 4; ++mt) acc[mt] = f32x4{0.f, 0.f, 0.f, 0.f};

    auto LOADH = [&](int i, long* a, long& b) {
        b = *reinterpret_cast<const long*>(wp + (size_t)i * 512);
        int kb = w * 16 + i;
#pragma unroll
        for (int mt = 0; mt < 4; ++mt)
            a[mt] = *reinterpret_cast<const long*>(ap + (size_t)(mt * 64 + kb) * 512);
    };

    long aA[4], bA, aB[4], bB;
    LOADH(0, aA, bA);
    for (int i = 0; i < 16; i += 2) {
        LOADH(i + 1, aB, bB);
#pragma unroll
        for (int mt = 0; mt < 4; ++mt)
            acc[mt] = __builtin_amdgcn_mfma_f32_16x16x32_fp8_fp8(aA[mt], bA, acc[mt], 0, 0, 0);
        if (i + 2 < 16) LOADH(i + 2, aA, bA);
#pragma unroll
        for (int mt = 0; mt < 4; ++mt)
            acc[mt] = __builtin_amdgcn_mfma_f32_16x16x32_fp8_fp8(aB[mt], bB, acc[mt], 0, 0, 0);
    }

    __shared__ float zs[4][64][17];
#pragma unroll
    for (int mt = 0; mt < 4; ++mt)
#pragma unroll
        for (int r = 0; r < 4; ++r)
            zs[w][mt * 16 + (lane >> 4) * 4 + r][lane & 15] = acc[mt][r];
    __syncthreads();

    const int tid = threadIdx.x;
    const int lr  = tid >> 2;
    const int u4  = (tid & 3) * 4;
    const int grow = mh * 64 + lr;
    const int gu   = ut * 16 + u4;

    float4 r;
    float* rr = &r.x;
#pragma unroll
    for (int e = 0; e < 4; ++e) {
        float v = (zs[0][lr][u4 + e] + zs[1][lr][u4 + e] +
                   zs[2][lr][u4 + e] + zs[3][lr][u4 + e]) * INV_SASB_ + bd[gu + e];
        rr[e] = v > 0.f ? v : 0.f;
    }
    *reinterpret_cast<float4*>(&y[(size_t)grow * U_ + gu]) = r;
}

// ---------------- out[b] = sigmoid(y[b,:] @ Wo + bo) ----------------
__global__ __launch_bounds__(256)
void head2(const float* __restrict__ y, const float* __restrict__ Wo,
           const float* __restrict__ bo, float* __restrict__ out) {
    __shared__ float red[256];
    const int b = blockIdx.x;
    const int tid = threadIdx.x;
    float s = 0.f;
    for (int u = tid; u < U_; u += 256) s += y[(size_t)b * U_ + u] * Wo[u];
    red[tid] = s;
    __syncthreads();
    for (int off = 128; off > 0; off >>= 1) {
        if (tid < off) red[tid] += red[tid + off];
        __syncthreads();
    }
    if (tid == 0) out[b] = 1.f / (1.f + __expf(-(red[0] + bo[0])));
}

extern "C" void kernel_launch(void* const* d_in, const int* in_sizes, int n_in,
                              void* d_out, int out_size, void* d_ws, size_t ws_size,
                              hipStream_t stream) {
    const int*   tokens = (const int*)  d_in[0];
    const float* emb    = (const float*)d_in[1];
    const float* W0     = (const float*)d_in[2];
    const float* U0     = (const float*)d_in[3];
    const float* b0     = (const float*)d_in[4];
    const float* W1     = (const float*)d_in[5];
    const float* U1     = (const float*)d_in[6];
    const float* b1     = (const float*)d_in[7];
    const float* Wd     = (const float*)d_in[8];
    const float* bd     = (const float*)d_in[9];
    const float* Wo     = (const float*)d_in[10];
    const float* bo     = (const float*)d_in[11];

    // ws layout (bytes); total ~62 MB
    char* base = (char*)d_ws;
    unsigned char* h0a = (unsigned char*)(base + 0);         // 256 KB (packed fp8)
    unsigned char* h1a = (unsigned char*)(base + 262144);    // 256 KB
    float*         c0  = (float*)        (base + 524288);    // 1 MB
    float*         c1  = (float*)        (base + 1572864);   // 1 MB
    unsigned char* h0b = (unsigned char*)(base + 2621440);   // 256 KB
    unsigned char* h1b = (unsigned char*)(base + 2883584);   // 256 KB
    unsigned char* Xp  = (unsigned char*)(base + 3145728);   // 2.62 MB
    float*         yb  = (float*)        (base + 3145728);   // overlays Xp (dead by head)
    unsigned char* W0p = (unsigned char*)(base + 5767168);   // 2 MB
    unsigned char* U0p = (unsigned char*)(base + 7864320);   // 16 MB
    unsigned char* W1p = (unsigned char*)(base + 24641536);  // 16 MB
    unsigned char* U1p = (unsigned char*)(base + 41418752);  // 16 MB
    unsigned char* Wdp = (unsigned char*)(base + 58195968);  // 4 MB

    // zero h0a, h1a, c0, c1 (contiguous 2.56 MB)
    hipMemsetAsync(d_ws, 0, 2621440, stream);

    embed_pack<<<(T_ * 8 * 8 * 64 + 255) / 256, 256, 0, stream>>>(tokens, emb, Xp);
    pack_all<<<27648, 256, 0, stream>>>(W0, U0, W1, U1, Wd,
                                        W0p, U0p, W1p, U1p, Wdp);

    for (int t = 0; t < T_; ++t) {
        const unsigned char* h0in  = (t & 1) ? h0b : h0a;
        unsigned char*       h0out = (t & 1) ? h0a : h0b;
        const unsigned char* h1in  = (t & 1) ? h1b : h1a;
        unsigned char*       h1out = (t & 1) ? h1a : h1b;
        lstm_step_t<8, 64><<<256, 512, 0, stream>>>(
            Xp + (size_t)t * 8 * 8 * 512, W0p, h0in, U0p, b0, c0, h0out);
        lstm_step_t<64, 64><<<256, 512, 0, stream>>>(
            h0out, W1p, h1in, U1p, b1, c1, h1out);
    }
    // t=79 (odd) wrote the 'a' buffers
    head_mfma<<<256, 256, 0, stream>>>(h1a, Wdp, bd, yb);
    head2<<<B_, 256, 0, stream>>>(yb, Wo, bo, (float*)d_out);
}